// Round 3
// baseline (3855.392 us; speedup 1.0000x reference)
//
#include <hip/hip_runtime.h>

// DecoderLSTM R3: unit-partitioned persistent kernel.
// 256 blocks = 32 ped-groups x 8 unit-groups. Block (pg,ug): 256 peds x 32 units.
// Weights: 80 KB/block, LDS-resident, loaded ONCE. h exchanged per step via
// global bf16 A-frag buffer (double-buffered); LN2 stats exchanged in fp32.
// Per-ped-group barrier: device-scope atomic counter (8 blocks, same XCD since
// pg = blockIdx & 31 and XCD = blockIdx % 8).

typedef float  f32x4  __attribute__((ext_vector_type(4)));
typedef short  short8 __attribute__((ext_vector_type(8)));
typedef __bf16 bf16x8 __attribute__((ext_vector_type(8)));

// d_ws layout (bytes)
#define WS_W     0           // 640 KB  : ws_w[ug8][kc10][gnt8][512] shorts
#define WS_HBUF  655360      // 8 MB    : hbuf[2][T512][kc8][512] shorts
#define WS_STATS 9043968     // 4 MB    : stats[2][ped8192][uh16][4] floats
#define WS_BIAS  13238272    // 4 KB
#define WS_SCAL  13242368    // 64 B
#define WS_CTR   13242432    // 128 B

__device__ __forceinline__ unsigned short f2bf(float f) {
  unsigned int u = __float_as_uint(f);
  u += 0x7FFFu + ((u >> 16) & 1u);   // RNE
  return (unsigned short)(u >> 16);
}

__device__ __forceinline__ float sigm(float x) {
  return __builtin_amdgcn_rcpf(1.0f + __expf(-x));
}

__device__ __forceinline__ float tanh_(float x) {
  float ax = fabsf(x);
  float t = __expf(-2.0f * ax);
  float r = (1.0f - t) * __builtin_amdgcn_rcpf(1.0f + t);
  return x >= 0.0f ? r : -r;
}

__device__ __forceinline__ f32x4 mfma16(short8 a, short8 b, f32x4 c) {
  return __builtin_amdgcn_mfma_f32_16x16x32_bf16(
      __builtin_bit_cast(bf16x8, a), __builtin_bit_cast(bf16x8, b), c, 0, 0, 0);
}

// ---- Prologue 1: weights -> B-frag-linear bf16, grouped by unit-group ------
// linear: ((ug*10 + kc)*8 + gnt)*512 + l*8 + j ; gnt = g*2 + nw
// row = g*256 + ug*32 + nw*16 + (l&15)
// kc<2: Wih col = kc*32 + (l>>4)*8 + j ; else Whh col = (kc-2)*32 + (l>>4)*8 + j
extern "C" __global__ void shuffle_weights(const float* __restrict__ Wih,
                                           const float* __restrict__ Whh,
                                           unsigned short* __restrict__ ws_w) {
  int t = blockIdx.x * 256 + threadIdx.x;  // 0..40959
  if (t >= 40960) return;
  int l = t & 63; int x = t >> 6;
  int gnt = x & 7; x >>= 3;
  int kc = x % 10;
  int ug = x / 10;
  int g = gnt >> 1, nw = gnt & 1;
  int row = g * 256 + ug * 32 + nw * 16 + (l & 15);
  unsigned short* dst = ws_w + (size_t)t * 8;
  if (kc < 2) {
    const float* src = Wih + row * 64 + kc * 32 + (l >> 4) * 8;
#pragma unroll
    for (int j = 0; j < 8; j++) dst[j] = f2bf(src[j]);
  } else {
    const float* src = Whh + row * 256 + (kc - 2) * 32 + (l >> 4) * 8;
#pragma unroll
    for (int j = 0; j < 8; j++) dst[j] = f2bf(src[j]);
  }
}

// ---- Prologue 1b: h0 (fp32 [8192][256]) -> hbuf[0] A-frag bf16 -------------
extern "C" __global__ void h0_convert(const float* __restrict__ h0,
                                      unsigned short* __restrict__ hbuf) {
  int t = blockIdx.x * 256 + threadIdx.x;  // 0..262143
  int lane = t & 63;
  int kc = (t >> 6) & 7;
  int T = t >> 9;  // 0..511
  int ped = T * 16 + (lane & 15);
  int unit = kc * 32 + (lane >> 4) * 8;
  const float* src = h0 + (size_t)ped * 256 + unit;
  float tf[8];
  *(float4*)&tf[0] = *(const float4*)(src);
  *(float4*)&tf[4] = *(const float4*)(src + 4);
  short8 sv;
#pragma unroll
  for (int j = 0; j < 8; j++) sv[j] = (short)f2bf(tf[j]);
  *(short8*)(hbuf + ((size_t)T * 8 + kc) * 512 + lane * 8) = sv;
}

// ---- Prologue 2: bias, scal, zero barrier counters -------------------------
extern "C" __global__ void prologue2(const float* __restrict__ b_ih,
                                     const float* __restrict__ b_hh,
                                     const float* __restrict__ ln2g,
                                     const float* __restrict__ ln2b,
                                     const float* __restrict__ posW,
                                     float* __restrict__ biasv,
                                     float* __restrict__ scal,
                                     int* __restrict__ ctr) {
  int t = threadIdx.x;  // 256 threads
#pragma unroll
  for (int k2 = 0; k2 < 4; k2++) {
    int n = t * 4 + k2;
    biasv[n] = b_ih[n] + b_hh[n];
  }
  if (t < 32) ctr[t] = 0;
  __shared__ float red[256][4];
  float g = ln2g[t], b = ln2b[t], p0 = posW[t], p1 = posW[256 + t];
  red[t][0] = b * p0;
  red[t][1] = b * p1;
  red[t][2] = g * p0;
  red[t][3] = g * p1;
  __syncthreads();
  for (int s = 128; s > 0; s >>= 1) {
    if (t < s) {
#pragma unroll
      for (int v = 0; v < 4; v++) red[t][v] += red[t + s][v];
    }
    __syncthreads();
  }
  if (t == 0) {
#pragma unroll
    for (int v = 0; v < 4; v++) scal[v] = red[0][v];
  }
}

// ---- Main persistent decoder ------------------------------------------------
extern "C" __global__ __launch_bounds__(512, 2) void decoder_main(
    const float* __restrict__ lpr,   // [8192][2]
    const float* __restrict__ c0,    // [8192][256]
    const float* __restrict__ embW,  // [64][2]
    const float* __restrict__ embB,  // [64]
    const float* __restrict__ ln1g, const float* __restrict__ ln1b,  // [2]
    const float* __restrict__ posW,  // [2][256]
    const float* __restrict__ posB,  // [2]
    const float* __restrict__ ln2g,  // [256]
    const unsigned short* __restrict__ ws_w,
    unsigned short* __restrict__ hbuf,   // [2][512][8][512] bf16
    float* __restrict__ stats,           // [2][8192][16][4]
    const float* __restrict__ biasv,     // [1024]
    const float* __restrict__ scal,      // [4] {K0,K1,SP0,SP1}
    int* __restrict__ ctr,               // [32]
    float* __restrict__ out)             // [30][8192][2]
{
  __shared__ unsigned short w_lds[10 * 8 * 512];   // 80 KB, loaded once
  __shared__ unsigned short x_stage[4 * 8 * 512];  // 32 KB: [mw][mt*2+kc2][512]

  const int pg = blockIdx.x & 31;   // ped group  (8 partner blocks same XCD)
  const int ug = blockIdx.x >> 5;   // unit group 0..7
  const int tid = threadIdx.x;
  const int w = tid >> 6;
  const int l = tid & 63;
  const int nw = w & 1;             // unit-half 0..1 (16 units each)
  const int mw = w >> 1;            // ped-quarter 0..3 (64 peds each)
  const int q = l >> 4;
  const int li = l & 15;

  // ---- load weights into LDS (once) ----
  {
    const unsigned short* src = ws_w + (size_t)ug * (10 * 8 * 512);
#pragma unroll
    for (int it = 0; it < 10; it++) {
      int idx = it * 4096 + tid * 8;
      *(short8*)(w_lds + idx) = *(const short8*)(src + idx);
    }
  }

  const float K0 = scal[0], K1 = scal[1], SP0 = scal[2], SP1 = scal[3];
  const float pb0 = posB[0], pb1 = posB[1];
  const float g10 = ln1g[0], g11 = ln1g[1], b10 = ln1b[0], b11 = ln1b[1];

  float bias_r[4];
#pragma unroll
  for (int g = 0; g < 4; g++)
    bias_r[g] = biasv[g * 256 + ug * 32 + nw * 16 + li];

  float Pp0, Pp1;  // ln2g[u]*posW[r][u] at this lane's unit
  {
    int u = ug * 32 + nw * 16 + li;
    float gg = ln2g[u];
    Pp0 = gg * posW[u];
    Pp1 = gg * posW[256 + u];
  }

  // ---- c0 into C-layout registers ----
  f32x4 c_r[4];  // [mt], components r
#pragma unroll
  for (int mt = 0; mt < 4; mt++)
#pragma unroll
    for (int r = 0; r < 4; r++) {
      int ped = pg * 256 + mw * 64 + mt * 16 + q * 4 + r;
      c_r[mt][r] = c0[(size_t)ped * 256 + ug * 32 + nw * 16 + li];
    }

  // ---- x0 = embed(LN1(lpr)) into x_stage (lane = ped 0..63 of this wave) ----
  {
    int pedg = pg * 256 + mw * 64 + l;
    float r0 = lpr[pedg * 2], r1 = lpr[pedg * 2 + 1];
    float d = 0.5f * (r0 - r1);
    float rs = rsqrtf(d * d + 1e-5f);
    float n0 = d * rs * g10 + b10;
    float n1 = -d * rs * g11 + b11;
    for (int k = 0; k < 64; k++) {
      float e = n0 * embW[k * 2] + n1 * embW[k * 2 + 1] + embB[k];
      e = e > 0.f ? e : 0.01f * e;
      x_stage[(mw * 8 + (l >> 4) * 2 + (k >> 5)) * 512 +
              ((l & 15) + 16 * ((k & 31) >> 3)) * 8 + (k & 7)] = f2bf(e);
    }
  }
  __syncthreads();

  const int Tbase = pg * 16 + mw * 4;
  const int loff = l * 8;

  for (int st = 0; st < 30; st++) {
    const int par = st & 1;
    const unsigned short* hb = hbuf + (size_t)par * (512 * 8 * 512);

    // prefetch first two h k-chunks (A-frags, direct from global)
    short8 ah[2][4];
#pragma unroll
    for (int mt = 0; mt < 4; mt++)
      ah[0][mt] = *(const short8*)(hb + ((size_t)(Tbase + mt) * 8 + 0) * 512 + loff);
#pragma unroll
    for (int mt = 0; mt < 4; mt++)
      ah[1][mt] = *(const short8*)(hb + ((size_t)(Tbase + mt) * 8 + 1) * 512 + loff);

    f32x4 acc[4][4];  // [gate][mt]
#pragma unroll
    for (int g = 0; g < 4; g++)
#pragma unroll
      for (int mt = 0; mt < 4; mt++)
        acc[g][mt] = (f32x4){bias_r[g], bias_r[g], bias_r[g], bias_r[g]};

    // x part: kc 0,1 (A from LDS x_stage)
#pragma unroll
    for (int kc2 = 0; kc2 < 2; kc2++) {
      short8 ax[4];
#pragma unroll
      for (int mt = 0; mt < 4; mt++)
        ax[mt] = *(const short8*)(x_stage + (mw * 8 + mt * 2 + kc2) * 512 + loff);
#pragma unroll
      for (int g = 0; g < 4; g++) {
        short8 b = *(const short8*)(w_lds + (kc2 * 8 + g * 2 + nw) * 512 + loff);
#pragma unroll
        for (int mt = 0; mt < 4; mt++)
          acc[g][mt] = mfma16(ax[mt], b, acc[g][mt]);
      }
    }
    // h part: kc 0..7 with rolling A prefetch
#pragma unroll
    for (int kc = 0; kc < 8; kc++) {
      short8 a[4];
#pragma unroll
      for (int mt = 0; mt < 4; mt++) a[mt] = ah[kc & 1][mt];
      if (kc < 6) {
#pragma unroll
        for (int mt = 0; mt < 4; mt++)
          ah[kc & 1][mt] = *(const short8*)(
              hb + ((size_t)(Tbase + mt) * 8 + (kc + 2)) * 512 + loff);
      }
#pragma unroll
      for (int g = 0; g < 4; g++) {
        short8 b = *(const short8*)(w_lds + ((2 + kc) * 8 + g * 2 + nw) * 512 + loff);
#pragma unroll
        for (int mt = 0; mt < 4; mt++)
          acc[g][mt] = mfma16(a[mt], b, acc[g][mt]);
      }
    }

    // ---- LSTM cell + h writes (A-frag, global) + stats ----
    const int parn = par ^ 1;
    unsigned short* hbn = hbuf + (size_t)parn * (512 * 8 * 512);
    float* stw = stats + ((size_t)par * 8192) * 64;  // stats[par]
#pragma unroll
    for (int mt = 0; mt < 4; mt++) {
      float sh[4], sh2[4], sA[4], sB[4];
#pragma unroll
      for (int r = 0; r < 4; r++) {
        float iv = sigm(acc[0][mt][r]);
        float fv = sigm(acc[1][mt][r]);
        float gv = tanh_(acc[2][mt][r]);
        float ov = sigm(acc[3][mt][r]);
        float cc = fv * c_r[mt][r] + iv * gv;
        c_r[mt][r] = cc;
        float hv = ov * tanh_(cc);
        // A-frag store: tile T=Tbase+mt, kc=ug, k = nw*16 + li
        hbn[((size_t)(Tbase + mt) * 8 + ug) * 512 +
            ((q * 4 + r) + 16 * (nw * 2 + (li >> 3))) * 8 + (li & 7)] = f2bf(hv);
        sh[r] = hv;
        sh2[r] = hv * hv;
        sA[r] = hv * Pp0;
        sB[r] = hv * Pp1;
      }
#pragma unroll
      for (int mask = 1; mask <= 8; mask <<= 1) {
#pragma unroll
        for (int r = 0; r < 4; r++) {
          sh[r] += __shfl_xor(sh[r], mask, 64);
          sh2[r] += __shfl_xor(sh2[r], mask, 64);
          sA[r] += __shfl_xor(sA[r], mask, 64);
          sB[r] += __shfl_xor(sB[r], mask, 64);
        }
      }
      if (li == 0) {
#pragma unroll
        for (int r = 0; r < 4; r++) {
          int pedg = pg * 256 + mw * 64 + mt * 16 + q * 4 + r;
          *(f32x4*)(stw + (size_t)pedg * 64 + (ug * 2 + nw) * 4) =
              (f32x4){sh[r], sh2[r], sA[r], sB[r]};
        }
      }
    }

    // ---- group barrier (8 blocks, device-scope) ----
    __threadfence();
    __syncthreads();
    if (tid == 0) {
      atomicAdd(&ctr[pg], 1);
      int target = 8 * (st + 1);
      while (__hip_atomic_load(&ctr[pg], __ATOMIC_RELAXED,
                               __HIP_MEMORY_SCOPE_AGENT) < target)
        __builtin_amdgcn_s_sleep(2);
    }
    __syncthreads();
    __threadfence();

    // ---- rel_st (out) + x_{st+1} ----
    {
      int pedg = pg * 256 + mw * 64 + l;
      const float* sr = stats + ((size_t)par * 8192 + pedg) * 64;
      float S = 0.f, S2 = 0.f, D0 = 0.f, D1 = 0.f;
#pragma unroll
      for (int uh = 0; uh < 16; uh++) {
        float4 v = *(const float4*)(sr + uh * 4);
        S += v.x; S2 += v.y; D0 += v.z; D1 += v.w;
      }
      float mu = S * (1.0f / 256.0f);
      float var = S2 * (1.0f / 256.0f) - mu * mu;
      float rsig = rsqrtf(var + 1e-5f);
      float rel0 = sigm(rsig * (D0 - mu * SP0) + K0 + pb0);
      float rel1 = sigm(rsig * (D1 - mu * SP1) + K1 + pb1);
      if (ug == 0 && nw == 0)
        *(float2*)(out + (size_t)st * 16384 + pedg * 2) = make_float2(rel0, rel1);
      if (st < 29) {
        float d = 0.5f * (rel0 - rel1);
        float rs = rsqrtf(d * d + 1e-5f);
        float n0 = d * rs * g10 + b10;
        float n1 = -d * rs * g11 + b11;
        for (int k = 0; k < 64; k++) {
          float e = n0 * embW[k * 2] + n1 * embW[k * 2 + 1] + embB[k];
          e = e > 0.f ? e : 0.01f * e;
          x_stage[(mw * 8 + (l >> 4) * 2 + (k >> 5)) * 512 +
                  ((l & 15) + 16 * ((k & 31) >> 3)) * 8 + (k & 7)] = f2bf(e);
        }
      }
    }
  }
}

extern "C" void kernel_launch(void* const* d_in, const int* in_sizes, int n_in,
                              void* d_out, int out_size, void* d_ws,
                              size_t ws_size, hipStream_t stream) {
  (void)in_sizes; (void)n_in; (void)out_size; (void)ws_size;
  const float* lpr  = (const float*)d_in[1];
  const float* h0   = (const float*)d_in[2];
  const float* c0   = (const float*)d_in[3];
  const float* Wih  = (const float*)d_in[4];
  const float* Whh  = (const float*)d_in[5];
  const float* b_ih = (const float*)d_in[6];
  const float* b_hh = (const float*)d_in[7];
  const float* embW = (const float*)d_in[8];
  const float* embB = (const float*)d_in[9];
  const float* ln1g = (const float*)d_in[10];
  const float* ln1b = (const float*)d_in[11];
  const float* posW = (const float*)d_in[12];
  const float* posB = (const float*)d_in[13];
  const float* ln2g = (const float*)d_in[14];
  const float* ln2b = (const float*)d_in[15];

  char* ws = (char*)d_ws;
  unsigned short* ws_w = (unsigned short*)(ws + WS_W);
  unsigned short* hbuf = (unsigned short*)(ws + WS_HBUF);
  float* statsp = (float*)(ws + WS_STATS);
  float* biasv  = (float*)(ws + WS_BIAS);
  float* scal   = (float*)(ws + WS_SCAL);
  int*   ctr    = (int*)(ws + WS_CTR);

  shuffle_weights<<<dim3(160), dim3(256), 0, stream>>>(Wih, Whh, ws_w);
  h0_convert<<<dim3(1024), dim3(256), 0, stream>>>(h0, hbuf);
  prologue2<<<dim3(1), dim3(256), 0, stream>>>(b_ih, b_hh, ln2g, ln2b, posW,
                                               biasv, scal, ctr);
  decoder_main<<<dim3(256), dim3(512), 0, stream>>>(
      lpr, c0, embW, embB, ln1g, ln1b, posW, posB, ln2g, ws_w, hbuf, statsp,
      biasv, scal, ctr, (float*)d_out);
}

// Round 5
// 889.607 us; speedup vs baseline: 4.3338x; 4.3338x over previous
//
#include <hip/hip_runtime.h>

// DecoderLSTM R5: unit-partitioned persistent kernel, compiler-tracked
// agent-scope atomic exchange (no inline asm).
// 256 blocks = 64 ped-groups x 4 unit-groups. Block: 128 peds x 64 units.
// Weights: 64 KB LDS + 24 short8 VGPRs/lane, loaded ONCE.
// h/stats exchanged via __hip_atomic relaxed AGENT ops (8B granules).
// Barrier: syncthreads (vmcnt drain) -> RELEASE fetch_add -> poll -> ACQUIRE.

typedef float  f32x4  __attribute__((ext_vector_type(4)));
typedef short  short8 __attribute__((ext_vector_type(8)));
typedef __bf16 bf16x8 __attribute__((ext_vector_type(8)));

#define WS_W     0                         // 640 KB
#define WS_HBUF  (640 * 1024)              // 8 MB: [2][512][8][512] shorts
#define WS_STATS (WS_HBUF + 8388608)       // 1 MB: [2][8192][4][4] floats
#define WS_BIAS  (WS_STATS + 1048576)      // 4 KB
#define WS_SCAL  (WS_BIAS + 4096)          // 64 B
#define WS_CTR   (WS_SCAL + 64)            // 64 * 256 B

typedef unsigned long long u64;

__device__ __forceinline__ unsigned short f2bf(float f) {
  unsigned int u = __float_as_uint(f);
  u += 0x7FFFu + ((u >> 16) & 1u);  // RNE
  return (unsigned short)(u >> 16);
}
__device__ __forceinline__ float sigm(float x) {
  return __builtin_amdgcn_rcpf(1.0f + __expf(-x));
}
__device__ __forceinline__ float tanh_(float x) {
  float ax = fabsf(x);
  float t = __expf(-2.0f * ax);
  float r = (1.0f - t) * __builtin_amdgcn_rcpf(1.0f + t);
  return x >= 0.0f ? r : -r;
}
__device__ __forceinline__ f32x4 mfma16(short8 a, short8 b, f32x4 c) {
  return __builtin_amdgcn_mfma_f32_16x16x32_bf16(
      __builtin_bit_cast(bf16x8, a), __builtin_bit_cast(bf16x8, b), c, 0, 0, 0);
}
__device__ __forceinline__ void st_ag(u64* p, u64 v) {
  __hip_atomic_store(p, v, __ATOMIC_RELAXED, __HIP_MEMORY_SCOPE_AGENT);
}
__device__ __forceinline__ u64 ld_ag(const u64* p) {
  return __hip_atomic_load((u64*)p, __ATOMIC_RELAXED, __HIP_MEMORY_SCOPE_AGENT);
}

// ---- Prologue 1: weights -> B-frag bf16, flat ((ug*10+kc)*16+g*4+uw)*512 ----
extern "C" __global__ void shuffle_weights(const float* __restrict__ Wih,
                                           const float* __restrict__ Whh,
                                           unsigned short* __restrict__ ws_w) {
  int t = blockIdx.x * 256 + threadIdx.x;  // 0..40959
  if (t >= 40960) return;
  int l = t & 63;
  int x = t >> 6;
  int uw = x & 3;
  int g = (x >> 2) & 3;
  int y = x >> 4;  // ug*10 + kc
  int kc = y % 10;
  int ug = y / 10;
  int row = g * 256 + ug * 64 + uw * 16 + (l & 15);
  unsigned short* dst = ws_w + (size_t)t * 8;
  if (kc < 2) {
    const float* src = Wih + row * 64 + kc * 32 + (l >> 4) * 8;
#pragma unroll
    for (int j = 0; j < 8; j++) dst[j] = f2bf(src[j]);
  } else {
    const float* src = Whh + row * 256 + (kc - 2) * 32 + (l >> 4) * 8;
#pragma unroll
    for (int j = 0; j < 8; j++) dst[j] = f2bf(src[j]);
  }
}

// ---- Prologue 2: bias, scal, zero padded counters ---------------------------
extern "C" __global__ void prologue2(const float* __restrict__ b_ih,
                                     const float* __restrict__ b_hh,
                                     const float* __restrict__ ln2g,
                                     const float* __restrict__ ln2b,
                                     const float* __restrict__ posW,
                                     float* __restrict__ biasv,
                                     float* __restrict__ scal,
                                     int* __restrict__ ctr) {
  int t = threadIdx.x;  // 256
#pragma unroll
  for (int k2 = 0; k2 < 4; k2++) {
    int n = t * 4 + k2;
    biasv[n] = b_ih[n] + b_hh[n];
  }
  if (t < 64) ctr[t * 64] = 0;
  __shared__ float red[256][4];
  float g = ln2g[t], b = ln2b[t], p0 = posW[t], p1 = posW[256 + t];
  red[t][0] = b * p0;
  red[t][1] = b * p1;
  red[t][2] = g * p0;
  red[t][3] = g * p1;
  __syncthreads();
  for (int s = 128; s > 0; s >>= 1) {
    if (t < s) {
#pragma unroll
      for (int v = 0; v < 4; v++) red[t][v] += red[t + s][v];
    }
    __syncthreads();
  }
  if (t == 0) {
#pragma unroll
    for (int v = 0; v < 4; v++) scal[v] = red[0][v];
  }
}

// ---- Main persistent decoder ------------------------------------------------
extern "C" __global__ __launch_bounds__(512, 2) void decoder_main(
    const float* __restrict__ lpr, const float* __restrict__ h0,
    const float* __restrict__ c0, const float* __restrict__ embW,
    const float* __restrict__ embB, const float* __restrict__ ln1g,
    const float* __restrict__ ln1b, const float* __restrict__ posW,
    const float* __restrict__ posB, const float* __restrict__ ln2g,
    const unsigned short* __restrict__ ws_w,
    unsigned short* __restrict__ hbuf,  // [2][512][8][512] shorts
    float* __restrict__ stats,          // [2][8192][4][4]
    const float* __restrict__ biasv, const float* __restrict__ scal,
    int* __restrict__ ctr, float* __restrict__ out) {
  __shared__ unsigned short w_lds[4 * 16 * 512];   // 64 KB, kc 0..3
  __shared__ unsigned short h_stage[8 * 8 * 512];  // 64 KB [Tl8][kc8][512]
  __shared__ unsigned short xh[16 * 512];          // 16 KB x-frags / h_out
  __shared__ float partials[128 * 16];             // 8 KB
  __shared__ float n01[128][2];

  const int bid = blockIdx.x;
  const int pg = bid >> 2, ug = bid & 3;
  const int tid = threadIdx.x;
  const int w = tid >> 6, l = tid & 63;
  const int uw = w & 3, pw = w >> 2;
  const int q = l >> 4, li = l & 15;
  const int P0 = pg * 128;
  const int loff = l * 8;
  const int u = ug * 64 + uw * 16 + li;

  // ---- weights: LDS part (kc 0..3) ----
  {
    const unsigned short* src = ws_w + (size_t)ug * 81920;
#pragma unroll
    for (int it = 0; it < 8; it++) {
      int f = tid + it * 512;
      *(short8*)(w_lds + f * 8) = *(const short8*)(src + f * 8);
    }
  }
  // ---- weights: register part (kc 4..9) ----
  short8 wr[6][4];
#pragma unroll
  for (int kk = 0; kk < 6; kk++)
#pragma unroll
    for (int g = 0; g < 4; g++)
      wr[kk][g] = *(const short8*)(ws_w + (size_t)ug * 81920 +
                                   ((kk + 4) * 16 + g * 4 + uw) * 512 + loff);

  const float K0 = scal[0], K1 = scal[1], SP0 = scal[2], SP1 = scal[3];
  const float pb0 = posB[0], pb1 = posB[1];
  const float g10 = ln1g[0], g11 = ln1g[1], b10 = ln1b[0], b11 = ln1b[1];

  float bias_r[4];
#pragma unroll
  for (int g = 0; g < 4; g++) bias_r[g] = biasv[g * 256 + u];
  float Pp0, Pp1;
  {
    float gg = ln2g[u];
    Pp0 = gg * posW[u];
    Pp1 = gg * posW[256 + u];
  }

  // ---- c0 ----
  f32x4 c_r[4];
#pragma unroll
  for (int mt = 0; mt < 4; mt++)
#pragma unroll
    for (int r = 0; r < 4; r++)
      c_r[mt][r] = c0[(size_t)(P0 + pw * 64 + mt * 16 + q * 4 + r) * 256 + u];

  // ---- h0 -> h_stage ----
#pragma unroll
  for (int it = 0; it < 8; it++) {
    int f = tid + it * 512;  // 0..4095
    int ll = f & 63, kc = (f >> 6) & 7, Tl = f >> 9;
    const float* src =
        h0 + (size_t)(P0 + Tl * 16 + (ll & 15)) * 256 + kc * 32 + (ll >> 4) * 8;
    float tf[8];
    *(float4*)&tf[0] = *(const float4*)(src);
    *(float4*)&tf[4] = *(const float4*)(src + 4);
    short8 sv;
#pragma unroll
    for (int j = 0; j < 8; j++) sv[j] = (short)f2bf(tf[j]);
    *(short8*)(h_stage + f * 8) = sv;
  }

  // ---- n01 from lpr ----
  if (tid < 128) {
    float r0 = lpr[(P0 + tid) * 2], r1 = lpr[(P0 + tid) * 2 + 1];
    float d = 0.5f * (r0 - r1);
    float rs = rsqrtf(d * d + 1e-5f);
    n01[tid][0] = d * rs * g10 + b10;
    n01[tid][1] = -d * rs * g11 + b11;
  }
  __syncthreads();

  // ---- x0 = embed(n01) into xh ----
  {
    const int pc = tid >> 2, s4 = tid & 3;
    float n0 = n01[pc][0], n1 = n01[pc][1];
    int Tl = pc >> 4, row = pc & 15;
#pragma unroll
    for (int jj = 0; jj < 16; jj++) {
      int k = s4 * 16 + jj;
      float e = n0 * embW[k * 2] + n1 * embW[k * 2 + 1] + embB[k];
      e = e > 0.f ? e : 0.01f * e;
      xh[(Tl * 2 + (k >> 5)) * 512 + (row + 16 * ((k & 31) >> 3)) * 8 + (k & 7)] =
          f2bf(e);
    }
  }
  __syncthreads();

  for (int st = 0; st < 30; st++) {
    const int par = st & 1, parn = par ^ 1;

    f32x4 acc[4][4];
#pragma unroll
    for (int g = 0; g < 4; g++)
#pragma unroll
      for (int mt = 0; mt < 4; mt++)
        acc[g][mt] = (f32x4){bias_r[g], bias_r[g], bias_r[g], bias_r[g]};

    // ---- x phase (reads xh) ----
#pragma unroll
    for (int kc2 = 0; kc2 < 2; kc2++) {
      short8 ax[4];
#pragma unroll
      for (int mt = 0; mt < 4; mt++)
        ax[mt] = *(const short8*)(xh + ((pw * 4 + mt) * 2 + kc2) * 512 + loff);
#pragma unroll
      for (int g = 0; g < 4; g++) {
        short8 b = *(const short8*)(w_lds + (kc2 * 16 + g * 4 + uw) * 512 + loff);
#pragma unroll
        for (int mt = 0; mt < 4; mt++)
          acc[g][mt] = mfma16(ax[mt], b, acc[g][mt]);
      }
    }
    __syncthreads();  // #1: xh reads done before h_out overlay writes

    // ---- h phase ----
#pragma unroll
    for (int kc = 0; kc < 8; kc++) {
      short8 a[4];
#pragma unroll
      for (int mt = 0; mt < 4; mt++)
        a[mt] = *(const short8*)(h_stage + ((pw * 4 + mt) * 8 + kc) * 512 + loff);
      if (kc < 2) {
#pragma unroll
        for (int g = 0; g < 4; g++) {
          short8 b =
              *(const short8*)(w_lds + ((kc + 2) * 16 + g * 4 + uw) * 512 + loff);
#pragma unroll
          for (int mt = 0; mt < 4; mt++)
            acc[g][mt] = mfma16(a[mt], b, acc[g][mt]);
        }
      } else {
#pragma unroll
        for (int g = 0; g < 4; g++)
#pragma unroll
          for (int mt = 0; mt < 4; mt++)
            acc[g][mt] = mfma16(a[mt], wr[kc - 2][g], acc[g][mt]);
      }
    }

    // ---- cell: c,h update; h_out (xh overlay) + partials ----
#pragma unroll
    for (int mt = 0; mt < 4; mt++) {
      float sh[4], sh2[4], sA[4], sB[4];
#pragma unroll
      for (int r = 0; r < 4; r++) {
        float iv = sigm(acc[0][mt][r]);
        float fv = sigm(acc[1][mt][r]);
        float gv = tanh_(acc[2][mt][r]);
        float ov = sigm(acc[3][mt][r]);
        float cc = fv * c_r[mt][r] + iv * gv;
        c_r[mt][r] = cc;
        float hv = ov * tanh_(cc);
        xh[((pw * 4 + mt) * 2 + (uw >> 1)) * 512 +
           ((q * 4 + r) + 16 * ((uw & 1) * 2 + (li >> 3))) * 8 + (li & 7)] =
            f2bf(hv);
        sh[r] = hv;
        sh2[r] = hv * hv;
        sA[r] = hv * Pp0;
        sB[r] = hv * Pp1;
      }
#pragma unroll
      for (int mask = 1; mask <= 8; mask <<= 1) {
#pragma unroll
        for (int r = 0; r < 4; r++) {
          sh[r] += __shfl_xor(sh[r], mask, 64);
          sh2[r] += __shfl_xor(sh2[r], mask, 64);
          sA[r] += __shfl_xor(sA[r], mask, 64);
          sB[r] += __shfl_xor(sB[r], mask, 64);
        }
      }
      if (li == 0) {
#pragma unroll
        for (int r = 0; r < 4; r++)
          *(f32x4*)(partials + (pw * 64 + mt * 16 + q * 4 + r) * 16 + uw * 4) =
              (f32x4){sh[r], sh2[r], sA[r], sB[r]};
      }
    }
    __syncthreads();  // #2

    // ---- stats combine + agent-store; h flush (agent-stores, 8B) ----
    if (tid < 128) {
      int pl = tid;
      f32x4 s = *(const f32x4*)(partials + pl * 16);
#pragma unroll
      for (int uu = 1; uu < 4; uu++) {
        f32x4 v = *(const f32x4*)(partials + pl * 16 + uu * 4);
        s.x += v.x;
        s.y += v.y;
        s.z += v.z;
        s.w += v.w;
      }
      u64* sw = (u64*)(stats + ((size_t)(par * 8192 + P0 + pl) * 4 + ug) * 4);
      float2 lo2 = make_float2(s.x, s.y), hi2 = make_float2(s.z, s.w);
      st_ag(sw + 0, __builtin_bit_cast(u64, lo2));
      st_ag(sw + 1, __builtin_bit_cast(u64, hi2));
    }
#pragma unroll
    for (int it = 0; it < 4; it++) {
      int f8 = tid + it * 512;  // ull slot 0..2047
      int s = f8 >> 1, half = f8 & 1;
      int ll = s & 63, chunk = s >> 6;
      int Tl = chunk >> 1, kcl = chunk & 1;
      u64 v = ((const u64*)xh)[f8];
      st_ag((u64*)(hbuf + (size_t)parn * 2097152 +
                   ((size_t)(pg * 8 + Tl) * 8 + ug * 2 + kcl) * 512 + ll * 8) +
                half,
            v);
    }
    __syncthreads();  // #3: compiler drains vmcnt before s_barrier

    if (tid == 0) {
      __hip_atomic_fetch_add(ctr + pg * 64, 1, __ATOMIC_RELEASE,
                             __HIP_MEMORY_SCOPE_AGENT);
      int target = 4 * (st + 1);
      while (__hip_atomic_load(ctr + pg * 64, __ATOMIC_RELAXED,
                               __HIP_MEMORY_SCOPE_AGENT) < target)
        __builtin_amdgcn_s_sleep(2);
      (void)__hip_atomic_load(ctr + pg * 64, __ATOMIC_ACQUIRE,
                              __HIP_MEMORY_SCOPE_AGENT);
    }
    __syncthreads();

    // ---- rel + out + n01 ----
    if (tid < 128) {
      int pl = tid, pedg = P0 + pl;
      const u64* sb = (const u64*)(stats + (size_t)(par * 8192 + pedg) * 16);
      float2 f01 = __builtin_bit_cast(float2, ld_ag(sb + 0));
      float2 fd0 = __builtin_bit_cast(float2, ld_ag(sb + 1));
      float2 f23 = __builtin_bit_cast(float2, ld_ag(sb + 2));
      float2 fd1 = __builtin_bit_cast(float2, ld_ag(sb + 3));
      float2 f45 = __builtin_bit_cast(float2, ld_ag(sb + 4));
      float2 fd2 = __builtin_bit_cast(float2, ld_ag(sb + 5));
      float2 f67 = __builtin_bit_cast(float2, ld_ag(sb + 6));
      float2 fd3 = __builtin_bit_cast(float2, ld_ag(sb + 7));
      float S = f01.x + f23.x + f45.x + f67.x;
      float S2 = f01.y + f23.y + f45.y + f67.y;
      float D0 = fd0.x + fd1.x + fd2.x + fd3.x;
      float D1 = fd0.y + fd1.y + fd2.y + fd3.y;
      float mu = S * (1.0f / 256.0f);
      float var = S2 * (1.0f / 256.0f) - mu * mu;
      float rsig = rsqrtf(var + 1e-5f);
      float rel0 = sigm(rsig * (D0 - mu * SP0) + K0 + pb0);
      float rel1 = sigm(rsig * (D1 - mu * SP1) + K1 + pb1);
      if (ug == 0)
        *(float2*)(out + (size_t)st * 16384 + pedg * 2) =
            make_float2(rel0, rel1);
      float d = 0.5f * (rel0 - rel1);
      float rs = rsqrtf(d * d + 1e-5f);
      n01[pl][0] = d * rs * g10 + b10;
      n01[pl][1] = -d * rs * g11 + b11;
    }
    __syncthreads();  // #4

    if (st < 29) {
      // next x = embed(n01) into xh
      {
        const int pc = tid >> 2, s4 = tid & 3;
        float n0 = n01[pc][0], n1 = n01[pc][1];
        int Tl = pc >> 4, row = pc & 15;
#pragma unroll
        for (int jj = 0; jj < 16; jj++) {
          int k = s4 * 16 + jj;
          float e = n0 * embW[k * 2] + n1 * embW[k * 2 + 1] + embB[k];
          e = e > 0.f ? e : 0.01f * e;
          xh[(Tl * 2 + (k >> 5)) * 512 + (row + 16 * ((k & 31) >> 3)) * 8 +
             (k & 7)] = f2bf(e);
        }
      }
      // h stage-in: contiguous 64 KB region, agent-loads -> LDS
      {
        const u64* src8 =
            (const u64*)(hbuf + (size_t)parn * 2097152 + (size_t)pg * 32768);
        u64* dst8 = (u64*)h_stage;
#pragma unroll
        for (int it = 0; it < 16; it++) {
          int f = tid + it * 512;
          dst8[f] = ld_ag(src8 + f);
        }
      }
    }
    __syncthreads();  // #5
  }
}

extern "C" void kernel_launch(void* const* d_in, const int* in_sizes, int n_in,
                              void* d_out, int out_size, void* d_ws,
                              size_t ws_size, hipStream_t stream) {
  (void)in_sizes; (void)n_in; (void)out_size; (void)ws_size;
  const float* lpr  = (const float*)d_in[1];
  const float* h0   = (const float*)d_in[2];
  const float* c0   = (const float*)d_in[3];
  const float* Wih  = (const float*)d_in[4];
  const float* Whh  = (const float*)d_in[5];
  const float* b_ih = (const float*)d_in[6];
  const float* b_hh = (const float*)d_in[7];
  const float* embW = (const float*)d_in[8];
  const float* embB = (const float*)d_in[9];
  const float* ln1g = (const float*)d_in[10];
  const float* ln1b = (const float*)d_in[11];
  const float* posW = (const float*)d_in[12];
  const float* posB = (const float*)d_in[13];
  const float* ln2g = (const float*)d_in[14];
  const float* ln2b = (const float*)d_in[15];

  char* ws = (char*)d_ws;
  unsigned short* ws_w = (unsigned short*)(ws + WS_W);
  unsigned short* hbuf = (unsigned short*)(ws + WS_HBUF);
  float* statsp = (float*)(ws + WS_STATS);
  float* biasv  = (float*)(ws + WS_BIAS);
  float* scal   = (float*)(ws + WS_SCAL);
  int*   ctr    = (int*)(ws + WS_CTR);

  shuffle_weights<<<dim3(160), dim3(256), 0, stream>>>(Wih, Whh, ws_w);
  prologue2<<<dim3(1), dim3(256), 0, stream>>>(b_ih, b_hh, ln2g, ln2b, posW,
                                               biasv, scal, ctr);
  decoder_main<<<dim3(256), dim3(512), 0, stream>>>(
      lpr, h0, c0, embW, embB, ln1g, ln1b, posW, posB, ln2g, ws_w, hbuf,
      statsp, biasv, scal, ctr, (float*)d_out);
}